// Round 2
// baseline (448.364 us; speedup 1.0000x reference)
//
#include <hip/hip_runtime.h>
#include <cstdint>
#include <cstddef>

// ---------------- types & helpers ----------------
typedef short bf16x8 __attribute__((ext_vector_type(8)));
typedef float f32x4 __attribute__((ext_vector_type(4)));

__device__ __forceinline__ float b2f(ushort u) {
    union { float f; uint32_t i; } v; v.i = ((uint32_t)u) << 16; return v.f;
}
__device__ __forceinline__ ushort f2b(float f) {
    union { float f; uint32_t i; } v; v.f = f;
    uint32_t r = v.i + 0x7FFFu + ((v.i >> 16) & 1u);
    return (ushort)(r >> 16);
}

#define ASYNC16(g, l) \
    __builtin_amdgcn_global_load_lds((const __attribute__((address_space(1))) void*)(g), \
                                     (__attribute__((address_space(3))) void*)(l), 16, 0, 0)

// ---------------- prep kernels ----------------
__global__ void cvt_x_kernel(const float4* __restrict__ x, ushort4* __restrict__ xb) {
    int i = blockIdx.x * 256 + threadIdx.x;
    float4 v = x[i];
    ushort4 o; o.x = f2b(v.x); o.y = f2b(v.y); o.z = f2b(v.z); o.w = f2b(v.w);
    xb[i] = o;
}

__global__ void prep_w_kernel(const float* __restrict__ w_in, const float* __restrict__ w_out,
                              const float* __restrict__ w_gx, const float* __restrict__ w_ga,
                              const float* __restrict__ b_gx, const float* __restrict__ b_ga,
                              const float* __restrict__ arp,
                              ushort* __restrict__ w_inT, ushort* __restrict__ w_outT,
                              ushort* __restrict__ WgT, float* __restrict__ bg,
                              float* __restrict__ sp) {
    int idx = blockIdx.x * 256 + threadIdx.x;  // 2,097,152 threads
    { int n = idx >> 10, k = idx & 1023; w_inT[idx]  = f2b(w_in[(size_t)k * 2048 + n]); }
    { int n = idx >> 11, k = idx & 2047; w_outT[idx] = f2b(w_out[(size_t)k * 1024 + n]); }
    if (idx < 524288) {  // combined block-diag gate weight, [cv][k] K-contig
        int cv = idx >> 8, k = idx & 255;
        int nb = cv >> 8, r = cv & 255;
        float v = (r < 128) ? w_gx[(size_t)nb * 32768 + (size_t)k * 128 + r]
                            : w_ga[(size_t)nb * 32768 + (size_t)k * 128 + (r - 128)];
        WgT[idx] = f2b(v);
    }
    if (idx < 2048) {
        int nb = idx >> 8, r = idx & 255;
        bg[idx] = (r < 128) ? b_gx[nb * 128 + r] : b_ga[nb * 128 + r - 128];
    }
    if (idx < 1024) {
        sp[idx] = log1pf(__expf(arp[idx]));  // softplus(a_real_param), args all < -2
    }
}

// ---------------- shared MFMA GEMM (C = A @ B^T + bias), 128x128 tile ----------------
// A: [M][K] bf16 K-contig (lda). B: [N][K] bf16 K-contig (ldb).
// EPI 0: store bf16 to ob (xh). EPI 1: sigmoid -> bf16, scatter to ob/ob1 (gx/ga).
// EPI 2: store f32 to o0 (y).
template<int EPI>
__launch_bounds__(256, 2)
__global__ void gemm_bt(const ushort* __restrict__ A, const ushort* __restrict__ B,
                        int M, int N, int K, int lda, int ldb,
                        const float* __restrict__ bias,
                        float* __restrict__ o0,
                        ushort* __restrict__ ob, ushort* __restrict__ ob1) {
    __shared__ ushort At[128 * 32];
    __shared__ ushort Bt[128 * 32];
    const int tid = threadIdx.x;
    const int lane = tid & 63;
    const int wave = tid >> 6;
    const int wr = wave >> 1, wc = wave & 1;
    const int m0 = blockIdx.y * 128, n0 = blockIdx.x * 128;

    const ushort* Ab = A;
    if (EPI == 1) Ab += (size_t)(n0 >> 8) * 256;  // block-diagonal: A column offset

    // staging: LDS linear dest = tid*16B; global src row = tid/4, 16B col chunk = tid%4
    const int arow = tid >> 2;
    const int acolb = (tid & 3) << 4;
    const char* ag0 = (const char*)Ab + ((size_t)(m0 + arow) * lda) * 2 + acolb;
    const char* ag1 = ag0 + (size_t)64 * lda * 2;
    const char* bg0 = (const char*)B + ((size_t)(n0 + arow) * ldb) * 2 + acolb;
    const char* bg1 = bg0 + (size_t)64 * ldb * 2;
    ushort* la0 = At + tid * 8; ushort* la1 = la0 + 2048;
    ushort* lb0 = Bt + tid * 8; ushort* lb1 = lb0 + 2048;

    f32x4 acc[4][4];
#pragma unroll
    for (int i = 0; i < 4; ++i)
#pragma unroll
        for (int j = 0; j < 4; ++j) acc[i][j] = (f32x4){0.f, 0.f, 0.f, 0.f};

    const int fm = lane & 15;
    const int fko = (lane >> 4) * 8;
    const ushort* Af = At + (wr * 64 + fm) * 32 + fko;
    const ushort* Bf = Bt + (wc * 64 + fm) * 32 + fko;

    const int nk = K >> 5;
    for (int kk = 0; kk < nk; ++kk) {
        __syncthreads();  // LDS reuse guard
        const size_t off = (size_t)kk * 64;
        ASYNC16(ag0 + off, la0);
        ASYNC16(ag1 + off, la1);
        ASYNC16(bg0 + off, lb0);
        ASYNC16(bg1 + off, lb1);
        __syncthreads();  // drains vmcnt before barrier
        bf16x8 af[4], bfv[4];
#pragma unroll
        for (int i = 0; i < 4; ++i) af[i]  = *(const bf16x8*)(Af + i * 512);
#pragma unroll
        for (int i = 0; i < 4; ++i) bfv[i] = *(const bf16x8*)(Bf + i * 512);
#pragma unroll
        for (int i = 0; i < 4; ++i)
#pragma unroll
            for (int j = 0; j < 4; ++j)
                acc[i][j] = __builtin_amdgcn_mfma_f32_16x16x32_bf16(af[i], bfv[j], acc[i][j], 0, 0, 0);
    }

    // epilogue: D[m][n], m = (lane>>4)*4 + r (+16*i), n = lane&15 (+16*j)
    const int r0 = (lane >> 4) * 4;
    const int cn = lane & 15;
#pragma unroll
    for (int j = 0; j < 4; ++j) {
        const int n = n0 + wc * 64 + j * 16 + cn;
        const float bv = bias[n];
        if (EPI == 1) {
            const int nb = n >> 8, rr = n & 255;
            const int c = nb * 128 + (rr & 127);
            ushort* base = (rr < 128) ? ob : ob1;
#pragma unroll
            for (int i = 0; i < 4; ++i) {
                const int mb = m0 + wr * 64 + i * 16 + r0;
#pragma unroll
                for (int r = 0; r < 4; ++r) {
                    float v = acc[i][j][r] + bv;
                    base[(size_t)(mb + r) * 1024 + c] = f2b(1.f / (1.f + __expf(-v)));
                }
            }
        } else if (EPI == 0) {
#pragma unroll
            for (int i = 0; i < 4; ++i) {
                const int mb = m0 + wr * 64 + i * 16 + r0;
#pragma unroll
                for (int r = 0; r < 4; ++r)
                    ob[(size_t)(mb + r) * N + n] = f2b(acc[i][j][r] + bv);
            }
        } else {
#pragma unroll
            for (int i = 0; i < 4; ++i) {
                const int mb = m0 + wr * 64 + i * 16 + r0;
#pragma unroll
                for (int r = 0; r < 4; ++r)
                    o0[(size_t)(mb + r) * N + n] = acc[i][j][r] + bv;
            }
        }
    }
}

// ---------------- scan (chunked, recompute) ----------------
// S=4096 split into 64 chunks of 64. Streams: b*1024 + c (4096 total).
// FINAL pass writes h (bf16) IN PLACE over xhb.
template<int FINAL>
__global__ void scan_chunk(const ushort* __restrict__ gx, const ushort* __restrict__ ga,
                           ushort* __restrict__ xhb,
                           const float* __restrict__ sp, const float* __restrict__ aim,
                           float2* __restrict__ carryA, float2* __restrict__ carryH,
                           const float2* __restrict__ prefixH,
                           float* __restrict__ hlast) {
    const int c = blockIdx.y * 256 + threadIdx.x;   // channel [0,1024)
    const int b = blockIdx.z;
    const int chunk = blockIdx.x;
    const int m0 = b * 4096 + chunk * 64;
    const float spc = sp[c], amc = aim[c];
    float Ar = 1.f, Ai = 0.f, Hr = 0.f, Hi = 0.f;
    if (FINAL) { float2 p = prefixH[chunk * 4096 + b * 1024 + c]; Hr = p.x; Hi = p.y; }
#pragma unroll 4
    for (int t = 0; t < 64; ++t) {
        const size_t m = (size_t)(m0 + t);
        float gxv = b2f(gx[m * 1024 + c]);
        float gav = b2f(ga[m * 1024 + c]);
        float xr = b2f(xhb[m * 2048 + c]);
        float xi = b2f(xhb[m * 2048 + c + 1024]);
        float la = -8.f * gav * spc;
        float er = __expf(la);
        float th = amc * gav;
        float sn, cs; __sincosf(th, &sn, &cs);
        float ar = er * cs, ai = er * sn;
        float nr = sqrtf(fmaxf(1.f - er * er, 1e-6f));
        float f = nr * gxv;
        float xcr = f * xr, xci = f * xi;
        float h2 = ar * Hr - ai * Hi + xcr;
        Hi = ar * Hi + ai * Hr + xci; Hr = h2;
        if (FINAL) {
            xhb[m * 2048 + c] = f2b(Hr);            // in-place: h over xh
            xhb[m * 2048 + c + 1024] = f2b(Hi);
        } else {
            float a2 = ar * Ar - ai * Ai; Ai = ar * Ai + ai * Ar; Ar = a2;
        }
    }
    if (!FINAL) {
        int s = chunk * 4096 + b * 1024 + c;
        carryA[s] = make_float2(Ar, Ai);
        carryH[s] = make_float2(Hr, Hi);
    } else if (chunk == 63) {
        hlast[b * 2048 + c] = Hr;
        hlast[b * 2048 + c + 1024] = Hi;
    }
}

__global__ void scan_top(const float2* __restrict__ cA, const float2* __restrict__ cH,
                         float2* __restrict__ pH) {
    const int s = blockIdx.x * 256 + threadIdx.x;  // 4096 streams
    float pr = 0.f, pi = 0.f;
    for (int ch = 0; ch < 64; ++ch) {
        pH[ch * 4096 + s] = make_float2(pr, pi);
        float2 A = cA[ch * 4096 + s];
        float2 H = cH[ch * 4096 + s];
        float t = A.x * pr - A.y * pi + H.x;
        pi = A.x * pi + A.y * pr + H.y;
        pr = t;
    }
}

// ws too small: encode ws_size (MB) into y so the bench error reveals it.
__global__ void ws_report_kernel(float* out, float code) {
    out[blockIdx.x * 256 + threadIdx.x] = code;
}

// ---------------- launch ----------------
extern "C" void kernel_launch(void* const* d_in, const int* in_sizes, int n_in,
                              void* d_out, int out_size, void* d_ws, size_t ws_size,
                              hipStream_t stream) {
    const float* x     = (const float*)d_in[0];
    const float* w_in  = (const float*)d_in[1];
    const float* b_in  = (const float*)d_in[2];
    const float* w_gx  = (const float*)d_in[3];
    const float* b_gx  = (const float*)d_in[4];
    const float* w_ga  = (const float*)d_in[5];
    const float* b_ga  = (const float*)d_in[6];
    const float* arp   = (const float*)d_in[7];
    const float* aip   = (const float*)d_in[8];
    const float* w_out = (const float*)d_in[9];
    const float* b_out = (const float*)d_in[10];
    float* out = (float*)d_out;

    // ---- workspace layout (~143 MB) ----
    // R0 (67MB): phase A = xb (first 33.5MB); phase B = gx | ga (bf16, 33.5MB each).
    //   Legal: xb dead after GEMM1; gate GEMM (writes R0) runs after GEMM1 on stream.
    // R1 (67MB): xhb (bf16); scan pass 2 overwrites it in place with h_m.
    char* p = (char*)d_ws;
    ushort* R0    = (ushort*)p; p += 67108864;
    ushort* xb    = R0;                          // 16384x1024 bf16 (phase A)
    ushort* gxb   = R0;                          // 16384x1024 bf16 (phase B)
    ushort* gab   = R0 + 16777216;               // 16384x1024 bf16 (phase B)
    ushort* xhb   = (ushort*)p; p += 67108864;   // 16384x2048 bf16, then h_m in place
    ushort* w_inT = (ushort*)p; p += 4194304;    // (2048x1024) K-contig
    ushort* w_outT= (ushort*)p; p += 4194304;    // (1024x2048) K-contig
    ushort* WgT   = (ushort*)p; p += 1048576;    // (2048x256)  K-contig
    float*  bg    = (float*)p;  p += 8192;
    float*  sp    = (float*)p;  p += 4096;
    float2* cA    = (float2*)p; p += 2097152;    // 64 chunks x 4096 streams
    float2* cH    = (float2*)p; p += 2097152;
    float2* pH    = (float2*)p; p += 2097152;
    size_t need = (size_t)(p - (char*)d_ws);
    if (ws_size < need) {
        float code = 1000.0f + (float)(ws_size >> 20);  // absmax err ~= 1000 + ws_MB
        ws_report_kernel<<<64, 256, 0, stream>>>(out, code);
        return;
    }

    cvt_x_kernel<<<16384, 256, 0, stream>>>((const float4*)x, (ushort4*)xb);
    prep_w_kernel<<<8192, 256, 0, stream>>>(w_in, w_out, w_gx, w_ga, b_gx, b_ga, arp,
                                            w_inT, w_outT, WgT, bg, sp);
    // xh = x @ w_in + b_in  (store bf16)
    gemm_bt<0><<<dim3(16, 128), 256, 0, stream>>>(xb, w_inT, 16384, 2048, 1024, 1024, 1024,
                                                  b_in, nullptr, xhb, nullptr);
    // gates = sigmoid(blockdiag(xh))  (bf16, over R0 — xb is dead now)
    gemm_bt<1><<<dim3(16, 128), 256, 0, stream>>>(xhb, WgT, 16384, 2048, 256, 2048, 256,
                                                  bg, nullptr, gxb, gab);
    // scan
    scan_chunk<0><<<dim3(64, 4, 4), 256, 0, stream>>>(gxb, gab, xhb, sp, aip, cA, cH,
                                                      nullptr, nullptr);
    scan_top<<<16, 256, 0, stream>>>(cA, cH, pH);
    scan_chunk<1><<<dim3(64, 4, 4), 256, 0, stream>>>(gxb, gab, xhb, sp, aip, nullptr, nullptr,
                                                      pH, out + 16777216);
    // y = h_m @ w_out + b_out   (h_m is xhb, in place)
    gemm_bt<2><<<dim3(8, 128), 256, 0, stream>>>(xhb, w_outT, 16384, 1024, 2048, 2048, 2048,
                                                 b_out, out, nullptr, nullptr);
}

// Round 4
// 425.496 us; speedup vs baseline: 1.0537x; 1.0537x over previous
//
#include <hip/hip_runtime.h>
#include <cstdint>
#include <cstddef>

// ---------------- types & helpers ----------------
typedef short bf16x8 __attribute__((ext_vector_type(8)));
typedef ushort ushort8 __attribute__((ext_vector_type(8)));
typedef float f32x4 __attribute__((ext_vector_type(4)));

__device__ __forceinline__ float b2f(ushort u) {
    union { float f; uint32_t i; } v; v.i = ((uint32_t)u) << 16; return v.f;
}
__device__ __forceinline__ ushort f2b(float f) {
    union { float f; uint32_t i; } v; v.f = f;
    uint32_t r = v.i + 0x7FFFu + ((v.i >> 16) & 1u);
    return (ushort)(r >> 16);
}

#define ASYNC16(g, l) \
    __builtin_amdgcn_global_load_lds((const __attribute__((address_space(1))) void*)(g), \
                                     (__attribute__((address_space(3))) void*)(l), 16, 0, 0)

// ---------------- prep kernels ----------------
__global__ void cvt_x_kernel(const float4* __restrict__ x, ushort4* __restrict__ xb) {
    int i = blockIdx.x * 256 + threadIdx.x;
    float4 v = x[i];
    ushort4 o; o.x = f2b(v.x); o.y = f2b(v.y); o.z = f2b(v.z); o.w = f2b(v.w);
    xb[i] = o;
}

// Tiled f32 -> bf16 transpose: in [R][C] f32 (row-major) -> out [C][R] bf16.
// R, C multiples of 64. grid (C/64, R/64, nbatch), block 256.
__global__ void transpose_cvt(const float* __restrict__ in, ushort* __restrict__ out,
                              int R, int C, int outStride,
                              size_t inBatch, size_t outBatch) {
    __shared__ float t[64 * 65];
    const int tid = threadIdx.x;
    const int r0 = blockIdx.y * 64, c0 = blockIdx.x * 64;
    const float* inp = in + blockIdx.z * inBatch;
    ushort* outp = out + blockIdx.z * outBatch;

    const int lr = tid >> 4;            // 0..15
    const int lc = (tid & 15) * 4;      // 0,4,..,60
#pragma unroll
    for (int i = 0; i < 4; ++i) {
        const int row = lr + i * 16;
        const float4 v = *(const float4*)&inp[(size_t)(r0 + row) * C + c0 + lc];
        t[row * 65 + lc + 0] = v.x;
        t[row * 65 + lc + 1] = v.y;
        t[row * 65 + lc + 2] = v.z;
        t[row * 65 + lc + 3] = v.w;
    }
    __syncthreads();
    const int oc = tid >> 2;            // out-row (= in col) 0..63
    const int orr = (tid & 3) * 16;     // out col base (= in row) 0,16,32,48
    ushort8 a, b;
#pragma unroll
    for (int i = 0; i < 8; ++i) a[i] = f2b(t[(orr + i) * 65 + oc]);
#pragma unroll
    for (int i = 0; i < 8; ++i) b[i] = f2b(t[(orr + 8 + i) * 65 + oc]);
    ushort* dst = outp + (size_t)(c0 + oc) * outStride + r0 + orr;
    *(ushort8*)dst = a;
    *(ushort8*)(dst + 8) = b;
}

__global__ void prep_small_kernel(const float* __restrict__ b_gx, const float* __restrict__ b_ga,
                                  const float* __restrict__ arp,
                                  float* __restrict__ bg, float* __restrict__ sp) {
    int idx = blockIdx.x * 256 + threadIdx.x;  // 2048
    {
        int nb = idx >> 8, r = idx & 255;
        bg[idx] = (r < 128) ? b_gx[nb * 128 + r] : b_ga[nb * 128 + r - 128];
    }
    if (idx < 1024) sp[idx] = log1pf(__expf(arp[idx]));
}

// ---------------- shared MFMA GEMM (C = A @ B^T + bias), 128x128 tile ----------------
// A: [M][K] bf16 K-contig (lda). B: [N][K] bf16 K-contig (ldb).
// 1D grid with bijective XCD swizzle; GX = 1<<gxbits column tiles.
// EPI 0: store bf16 to ob (xh). EPI 1: sigmoid -> bf16, scatter to ob/ob1 (gx/ga).
// EPI 2: store f32 to o0 (y).
template<int EPI>
__launch_bounds__(256, 2)
__global__ void gemm_bt(const ushort* __restrict__ A, const ushort* __restrict__ B,
                        int M, int N, int K, int lda, int ldb, int gxbits,
                        const float* __restrict__ bias,
                        float* __restrict__ o0,
                        ushort* __restrict__ ob, ushort* __restrict__ ob1) {
    __shared__ ushort At[128 * 32];
    __shared__ ushort Bt[128 * 32];
    const int tid = threadIdx.x;
    const int lane = tid & 63;
    const int wave = tid >> 6;
    const int wr = wave >> 1, wc = wave & 1;

    // XCD-aware bijective swizzle (gridDim.x % 8 == 0): each XCD gets a
    // contiguous swz chunk -> A row-panels reused within one L2.
    const int swz = (blockIdx.x & 7) * (gridDim.x >> 3) + (blockIdx.x >> 3);
    const int m0 = (swz >> gxbits) * 128;
    const int n0 = (swz & ((1 << gxbits) - 1)) * 128;

    const ushort* Ab = A;
    if (EPI == 1) Ab += (size_t)(n0 >> 8) * 256;  // block-diagonal: A column offset

    // staging: LDS linear dest = tid*16B; global src row = tid/4, 16B col chunk = tid%4
    const int arow = tid >> 2;
    const int acolb = (tid & 3) << 4;
    const char* ag0 = (const char*)Ab + ((size_t)(m0 + arow) * lda) * 2 + acolb;
    const char* ag1 = ag0 + (size_t)64 * lda * 2;
    const char* bgp0 = (const char*)B + ((size_t)(n0 + arow) * ldb) * 2 + acolb;
    const char* bgp1 = bgp0 + (size_t)64 * ldb * 2;
    ushort* la0 = At + tid * 8; ushort* la1 = la0 + 2048;
    ushort* lb0 = Bt + tid * 8; ushort* lb1 = lb0 + 2048;

    f32x4 acc[4][4];
#pragma unroll
    for (int i = 0; i < 4; ++i)
#pragma unroll
        for (int j = 0; j < 4; ++j) acc[i][j] = (f32x4){0.f, 0.f, 0.f, 0.f};

    const int fm = lane & 15;
    const int fko = (lane >> 4) * 8;
    const ushort* Af = At + (wr * 64 + fm) * 32 + fko;
    const ushort* Bf = Bt + (wc * 64 + fm) * 32 + fko;

    const int nk = K >> 5;
    for (int kk = 0; kk < nk; ++kk) {
        __syncthreads();  // LDS reuse guard
        const size_t off = (size_t)kk * 64;
        ASYNC16(ag0 + off, la0);
        ASYNC16(ag1 + off, la1);
        ASYNC16(bgp0 + off, lb0);
        ASYNC16(bgp1 + off, lb1);
        __syncthreads();  // drains vmcnt before barrier
        bf16x8 af[4], bfv[4];
#pragma unroll
        for (int i = 0; i < 4; ++i) af[i]  = *(const bf16x8*)(Af + i * 512);
#pragma unroll
        for (int i = 0; i < 4; ++i) bfv[i] = *(const bf16x8*)(Bf + i * 512);
#pragma unroll
        for (int i = 0; i < 4; ++i)
#pragma unroll
            for (int j = 0; j < 4; ++j)
                acc[i][j] = __builtin_amdgcn_mfma_f32_16x16x32_bf16(af[i], bfv[j], acc[i][j], 0, 0, 0);
    }

    // epilogue: D[m][n], m = (lane>>4)*4 + r (+16*i), n = lane&15 (+16*j)
    const int r0 = (lane >> 4) * 4;
    const int cn = lane & 15;
#pragma unroll
    for (int j = 0; j < 4; ++j) {
        const int n = n0 + wc * 64 + j * 16 + cn;
        const float bv = bias[n];
        if (EPI == 1) {
            const int nb = n >> 8, rr = n & 255;
            const int c = nb * 128 + (rr & 127);
            ushort* base = (rr < 128) ? ob : ob1;
#pragma unroll
            for (int i = 0; i < 4; ++i) {
                const int mb = m0 + wr * 64 + i * 16 + r0;
#pragma unroll
                for (int r = 0; r < 4; ++r) {
                    float v = acc[i][j][r] + bv;
                    base[(size_t)(mb + r) * 1024 + c] = f2b(1.f / (1.f + __expf(-v)));
                }
            }
        } else if (EPI == 0) {
#pragma unroll
            for (int i = 0; i < 4; ++i) {
                const int mb = m0 + wr * 64 + i * 16 + r0;
#pragma unroll
                for (int r = 0; r < 4; ++r)
                    ob[(size_t)(mb + r) * N + n] = f2b(acc[i][j][r] + bv);
            }
        } else {
#pragma unroll
            for (int i = 0; i < 4; ++i) {
                const int mb = m0 + wr * 64 + i * 16 + r0;
#pragma unroll
                for (int r = 0; r < 4; ++r)
                    o0[(size_t)(mb + r) * N + n] = acc[i][j][r] + bv;
            }
        }
    }
}

// ---------------- scan (chunked, recompute, 2 channels/thread) ----------------
// S=4096 split into 64 chunks of 64. Streams: b*1024 + c (4096 total).
// FINAL pass writes h (bf16) IN PLACE over xhb.
template<int FINAL>
__global__ void scan_chunk(const ushort2* __restrict__ gx2, const ushort2* __restrict__ ga2,
                           ushort2* __restrict__ xhb2,
                           const float* __restrict__ sp, const float* __restrict__ aim,
                           float2* __restrict__ carryA, float2* __restrict__ carryH,
                           const float2* __restrict__ prefixH,
                           float* __restrict__ hlast) {
    const int c2 = blockIdx.y * 256 + threadIdx.x;  // pair index [0,512)
    const int c = c2 * 2;                           // channel [0,1024)
    const int b = blockIdx.z;
    const int chunk = blockIdx.x;
    const int m0 = b * 4096 + chunk * 64;
    const float sp0 = sp[c], sp1 = sp[c + 1];
    const float am0 = aim[c], am1 = aim[c + 1];
    float Ar0 = 1.f, Ai0 = 0.f, Hr0 = 0.f, Hi0 = 0.f;
    float Ar1 = 1.f, Ai1 = 0.f, Hr1 = 0.f, Hi1 = 0.f;
    if (FINAL) {
        float2 p0 = prefixH[chunk * 4096 + b * 1024 + c];
        float2 p1 = prefixH[chunk * 4096 + b * 1024 + c + 1];
        Hr0 = p0.x; Hi0 = p0.y; Hr1 = p1.x; Hi1 = p1.y;
    }
#pragma unroll 4
    for (int t = 0; t < 64; ++t) {
        const size_t m = (size_t)(m0 + t);
        const ushort2 gv = gx2[m * 512 + c2];
        const ushort2 av = ga2[m * 512 + c2];
        const ushort2 xrv = xhb2[m * 1024 + c2];
        const ushort2 xiv = xhb2[m * 1024 + 512 + c2];
        // channel 0
        {
            float gav = b2f(av.x);
            float er = __expf(-8.f * gav * sp0);
            float sn, cs; __sincosf(am0 * gav, &sn, &cs);
            float f = sqrtf(fmaxf(1.f - er * er, 1e-6f)) * b2f(gv.x);
            float ar = er * cs, ai = er * sn;
            float xcr = f * b2f(xrv.x), xci = f * b2f(xiv.x);
            float h2 = ar * Hr0 - ai * Hi0 + xcr;
            Hi0 = ar * Hi0 + ai * Hr0 + xci; Hr0 = h2;
            if (!FINAL) { float a2 = ar * Ar0 - ai * Ai0; Ai0 = ar * Ai0 + ai * Ar0; Ar0 = a2; }
        }
        // channel 1
        {
            float gav = b2f(av.y);
            float er = __expf(-8.f * gav * sp1);
            float sn, cs; __sincosf(am1 * gav, &sn, &cs);
            float f = sqrtf(fmaxf(1.f - er * er, 1e-6f)) * b2f(gv.y);
            float ar = er * cs, ai = er * sn;
            float xcr = f * b2f(xrv.y), xci = f * b2f(xiv.y);
            float h2 = ar * Hr1 - ai * Hi1 + xcr;
            Hi1 = ar * Hi1 + ai * Hr1 + xci; Hr1 = h2;
            if (!FINAL) { float a2 = ar * Ar1 - ai * Ai1; Ai1 = ar * Ai1 + ai * Ar1; Ar1 = a2; }
        }
        if (FINAL) {
            ushort2 hr; hr.x = f2b(Hr0); hr.y = f2b(Hr1);
            ushort2 hi; hi.x = f2b(Hi0); hi.y = f2b(Hi1);
            xhb2[m * 1024 + c2] = hr;
            xhb2[m * 1024 + 512 + c2] = hi;
        }
    }
    if (!FINAL) {
        int s = chunk * 4096 + b * 1024 + c;
        carryA[s] = make_float2(Ar0, Ai0);
        carryA[s + 1] = make_float2(Ar1, Ai1);
        carryH[s] = make_float2(Hr0, Hi0);
        carryH[s + 1] = make_float2(Hr1, Hi1);
    } else if (chunk == 63) {
        hlast[b * 2048 + c] = Hr0;
        hlast[b * 2048 + c + 1] = Hr1;
        hlast[b * 2048 + c + 1024] = Hi0;
        hlast[b * 2048 + c + 1025] = Hi1;
    }
}

__global__ void scan_top(const float2* __restrict__ cA, const float2* __restrict__ cH,
                         float2* __restrict__ pH) {
    const int s = blockIdx.x * 256 + threadIdx.x;  // 4096 streams
    float pr = 0.f, pi = 0.f;
    for (int ch = 0; ch < 64; ++ch) {
        pH[ch * 4096 + s] = make_float2(pr, pi);
        float2 A = cA[ch * 4096 + s];
        float2 H = cH[ch * 4096 + s];
        float t = A.x * pr - A.y * pi + H.x;
        pi = A.x * pi + A.y * pr + H.y;
        pr = t;
    }
}

// ws too small: encode ws_size (MB) into y so the bench error reveals it.
__global__ void ws_report_kernel(float* out, float code) {
    out[blockIdx.x * 256 + threadIdx.x] = code;
}

// ---------------- launch ----------------
extern "C" void kernel_launch(void* const* d_in, const int* in_sizes, int n_in,
                              void* d_out, int out_size, void* d_ws, size_t ws_size,
                              hipStream_t stream) {
    const float* x     = (const float*)d_in[0];
    const float* w_in  = (const float*)d_in[1];
    const float* b_in  = (const float*)d_in[2];
    const float* w_gx  = (const float*)d_in[3];
    const float* b_gx  = (const float*)d_in[4];
    const float* w_ga  = (const float*)d_in[5];
    const float* b_ga  = (const float*)d_in[6];
    const float* arp   = (const float*)d_in[7];
    const float* aip   = (const float*)d_in[8];
    const float* w_out = (const float*)d_in[9];
    const float* b_out = (const float*)d_in[10];
    float* out = (float*)d_out;

    // ---- workspace layout (~143 MB) ----
    char* p = (char*)d_ws;
    ushort* R0    = (ushort*)p; p += 67108864;
    ushort* xb    = R0;                          // 16384x1024 bf16 (phase A)
    ushort* gxb   = R0;                          // 16384x1024 bf16 (phase B)
    ushort* gab   = R0 + 16777216;               // 16384x1024 bf16 (phase B)
    ushort* xhb   = (ushort*)p; p += 67108864;   // 16384x2048 bf16, then h_m in place
    ushort* w_inT = (ushort*)p; p += 4194304;    // (2048x1024) K-contig
    ushort* w_outT= (ushort*)p; p += 4194304;    // (1024x2048) K-contig
    ushort* WgT   = (ushort*)p; p += 1048576;    // (2048x256)  K-contig
    float*  bg    = (float*)p;  p += 8192;
    float*  sp    = (float*)p;  p += 4096;
    float2* cA    = (float2*)p; p += 2097152;    // 64 chunks x 4096 streams
    float2* cH    = (float2*)p; p += 2097152;
    float2* pH    = (float2*)p; p += 2097152;
    size_t need = (size_t)(p - (char*)d_ws);
    if (ws_size < need) {
        float code = 1000.0f + (float)(ws_size >> 20);
        ws_report_kernel<<<64, 256, 0, stream>>>(out, code);
        return;
    }

    cvt_x_kernel<<<16384, 256, 0, stream>>>((const float4*)x, (ushort4*)xb);
    // weight transposes (f32 -> bf16, K-contig)
    transpose_cvt<<<dim3(32, 16, 1), 256, 0, stream>>>(w_in, w_inT, 1024, 2048, 1024, 0, 0);
    transpose_cvt<<<dim3(16, 32, 1), 256, 0, stream>>>(w_out, w_outT, 2048, 1024, 2048, 0, 0);
    transpose_cvt<<<dim3(2, 4, 8), 256, 0, stream>>>(w_gx, WgT, 256, 128, 256, 32768, 65536);
    transpose_cvt<<<dim3(2, 4, 8), 256, 0, stream>>>(w_ga, WgT + 32768, 256, 128, 256, 32768, 65536);
    prep_small_kernel<<<8, 256, 0, stream>>>(b_gx, b_ga, arp, bg, sp);

    // xh = x @ w_in + b_in  (store bf16)   grid 16x128 -> 2048 blocks, GX=16
    gemm_bt<0><<<2048, 256, 0, stream>>>(xb, w_inT, 16384, 2048, 1024, 1024, 1024, 4,
                                         b_in, nullptr, xhb, nullptr);
    // gates = sigmoid(blockdiag(xh))  (bf16, over R0 — xb dead)   GX=16
    gemm_bt<1><<<2048, 256, 0, stream>>>(xhb, WgT, 16384, 2048, 256, 2048, 256, 4,
                                         bg, nullptr, gxb, gab);
    // scan
    scan_chunk<0><<<dim3(64, 2, 4), 256, 0, stream>>>((const ushort2*)gxb, (const ushort2*)gab,
                                                      (ushort2*)xhb, sp, aip, cA, cH,
                                                      nullptr, nullptr);
    scan_top<<<16, 256, 0, stream>>>(cA, cH, pH);
    scan_chunk<1><<<dim3(64, 2, 4), 256, 0, stream>>>((const ushort2*)gxb, (const ushort2*)gab,
                                                      (ushort2*)xhb, sp, aip, nullptr, nullptr,
                                                      pH, out + 16777216);
    // y = h_m @ w_out + b_out   (h_m is xhb, in place)   GX=8
    gemm_bt<2><<<1024, 256, 0, stream>>>(xhb, w_outT, 16384, 1024, 2048, 2048, 2048, 3,
                                         b_out, out, nullptr, nullptr);
}

// Round 5
// 417.894 us; speedup vs baseline: 1.0729x; 1.0182x over previous
//
#include <hip/hip_runtime.h>
#include <cstdint>
#include <cstddef>

// ---------------- types & helpers ----------------
typedef short bf16x8 __attribute__((ext_vector_type(8)));
typedef ushort ushort8 __attribute__((ext_vector_type(8)));
typedef float f32x4 __attribute__((ext_vector_type(4)));

__device__ __forceinline__ float b2f(ushort u) {
    union { float f; uint32_t i; } v; v.i = ((uint32_t)u) << 16; return v.f;
}
__device__ __forceinline__ ushort f2b(float f) {
    union { float f; uint32_t i; } v; v.f = f;
    uint32_t r = v.i + 0x7FFFu + ((v.i >> 16) & 1u);
    return (ushort)(r >> 16);
}

#define ASYNC16(g, l) \
    __builtin_amdgcn_global_load_lds((const __attribute__((address_space(1))) void*)(g), \
                                     (__attribute__((address_space(3))) void*)(l), 16, 0, 0)

// ---------------- prep kernels ----------------
__global__ void cvt_x_kernel(const float4* __restrict__ x, ushort4* __restrict__ xb) {
    int i = blockIdx.x * 256 + threadIdx.x;
    float4 v = x[i];
    ushort4 o; o.x = f2b(v.x); o.y = f2b(v.y); o.z = f2b(v.z); o.w = f2b(v.w);
    xb[i] = o;
}

// Tiled f32 -> bf16 transpose: in [R][C] f32 (row-major) -> out [C][R] bf16.
// R, C multiples of 64. grid (C/64, R/64, nbatch), block 256.
__global__ void transpose_cvt(const float* __restrict__ in, ushort* __restrict__ out,
                              int R, int C, int outStride,
                              size_t inBatch, size_t outBatch) {
    __shared__ float t[64 * 65];
    const int tid = threadIdx.x;
    const int r0 = blockIdx.y * 64, c0 = blockIdx.x * 64;
    const float* inp = in + blockIdx.z * inBatch;
    ushort* outp = out + blockIdx.z * outBatch;

    const int lr = tid >> 4;            // 0..15
    const int lc = (tid & 15) * 4;      // 0,4,..,60
#pragma unroll
    for (int i = 0; i < 4; ++i) {
        const int row = lr + i * 16;
        const float4 v = *(const float4*)&inp[(size_t)(r0 + row) * C + c0 + lc];
        t[row * 65 + lc + 0] = v.x;
        t[row * 65 + lc + 1] = v.y;
        t[row * 65 + lc + 2] = v.z;
        t[row * 65 + lc + 3] = v.w;
    }
    __syncthreads();
    const int oc = tid >> 2;            // out-row (= in col) 0..63
    const int orr = (tid & 3) * 16;     // out col base (= in row) 0,16,32,48
    ushort8 a, b;
#pragma unroll
    for (int i = 0; i < 8; ++i) a[i] = f2b(t[(orr + i) * 65 + oc]);
#pragma unroll
    for (int i = 0; i < 8; ++i) b[i] = f2b(t[(orr + 8 + i) * 65 + oc]);
    ushort* dst = outp + (size_t)(c0 + oc) * outStride + r0 + orr;
    *(ushort8*)dst = a;
    *(ushort8*)(dst + 8) = b;
}

__global__ void prep_small_kernel(const float* __restrict__ b_gx, const float* __restrict__ b_ga,
                                  const float* __restrict__ arp,
                                  float* __restrict__ bg, float* __restrict__ sp) {
    int idx = blockIdx.x * 256 + threadIdx.x;  // 2048
    {
        int nb = idx >> 8, r = idx & 255;
        bg[idx] = (r < 128) ? b_gx[nb * 128 + r] : b_ga[nb * 128 + r - 128];
    }
    if (idx < 1024) sp[idx] = log1pf(__expf(arp[idx]));
}

// ---------------- shared MFMA GEMM (C = A @ B^T + bias), 128x128 tile ----------------
// A: [M][K] bf16 K-contig (lda). B: [N][K] bf16 K-contig (ldb).
// 1D grid with bijective XCD swizzle; GX = 1<<gxbits column tiles.
// EPI 0: store bf16 to ob (xh). EPI 1: sigmoid -> bf16, INTERLEAVED (gx,ga) to ob.
// EPI 2: store f32 to o0 (y).
template<int EPI>
__launch_bounds__(256, 2)
__global__ void gemm_bt(const ushort* __restrict__ A, const ushort* __restrict__ B,
                        int M, int N, int K, int lda, int ldb, int gxbits,
                        const float* __restrict__ bias,
                        float* __restrict__ o0,
                        ushort* __restrict__ ob) {
    __shared__ ushort At[128 * 32];
    __shared__ ushort Bt[128 * 32];
    const int tid = threadIdx.x;
    const int lane = tid & 63;
    const int wave = tid >> 6;
    const int wr = wave >> 1, wc = wave & 1;

    // XCD-aware bijective swizzle (gridDim.x % 8 == 0): each XCD gets a
    // contiguous swz chunk -> A row-panels reused within one L2.
    const int swz = (blockIdx.x & 7) * (gridDim.x >> 3) + (blockIdx.x >> 3);
    const int m0 = (swz >> gxbits) * 128;
    const int n0 = (swz & ((1 << gxbits) - 1)) * 128;

    const ushort* Ab = A;
    if (EPI == 1) Ab += (size_t)(n0 >> 8) * 256;  // block-diagonal: A column offset

    // staging: LDS linear dest = tid*16B; global src row = tid/4, 16B col chunk = tid%4
    const int arow = tid >> 2;
    const int acolb = (tid & 3) << 4;
    const char* ag0 = (const char*)Ab + ((size_t)(m0 + arow) * lda) * 2 + acolb;
    const char* ag1 = ag0 + (size_t)64 * lda * 2;
    const char* bgp0 = (const char*)B + ((size_t)(n0 + arow) * ldb) * 2 + acolb;
    const char* bgp1 = bgp0 + (size_t)64 * ldb * 2;
    ushort* la0 = At + tid * 8; ushort* la1 = la0 + 2048;
    ushort* lb0 = Bt + tid * 8; ushort* lb1 = lb0 + 2048;

    f32x4 acc[4][4];
#pragma unroll
    for (int i = 0; i < 4; ++i)
#pragma unroll
        for (int j = 0; j < 4; ++j) acc[i][j] = (f32x4){0.f, 0.f, 0.f, 0.f};

    const int fm = lane & 15;
    const int fko = (lane >> 4) * 8;
    const ushort* Af = At + (wr * 64 + fm) * 32 + fko;
    const ushort* Bf = Bt + (wc * 64 + fm) * 32 + fko;

    const int nk = K >> 5;
    for (int kk = 0; kk < nk; ++kk) {
        __syncthreads();  // LDS reuse guard
        const size_t off = (size_t)kk * 64;
        ASYNC16(ag0 + off, la0);
        ASYNC16(ag1 + off, la1);
        ASYNC16(bgp0 + off, lb0);
        ASYNC16(bgp1 + off, lb1);
        __syncthreads();  // drains vmcnt before barrier
        bf16x8 af[4], bfv[4];
#pragma unroll
        for (int i = 0; i < 4; ++i) af[i]  = *(const bf16x8*)(Af + i * 512);
#pragma unroll
        for (int i = 0; i < 4; ++i) bfv[i] = *(const bf16x8*)(Bf + i * 512);
#pragma unroll
        for (int i = 0; i < 4; ++i)
#pragma unroll
            for (int j = 0; j < 4; ++j)
                acc[i][j] = __builtin_amdgcn_mfma_f32_16x16x32_bf16(af[i], bfv[j], acc[i][j], 0, 0, 0);
    }

    // epilogue: D[m][n], m = (lane>>4)*4 + r (+16*i), n = lane&15 (+16*j)
    const int r0 = (lane >> 4) * 4;
    const int cn = lane & 15;
#pragma unroll
    for (int j = 0; j < 4; ++j) {
        const int n = n0 + wc * 64 + j * 16 + cn;
        const float bv = bias[n];
        if (EPI == 1) {
            const int nb = n >> 8, rr = n & 255;
            const int c = nb * 128 + (rr & 127);
            const int wh = (rr >> 7) & 1;      // 0 = gx, 1 = ga
#pragma unroll
            for (int i = 0; i < 4; ++i) {
                const int mb = m0 + wr * 64 + i * 16 + r0;
#pragma unroll
                for (int r = 0; r < 4; ++r) {
                    float v = acc[i][j][r] + bv;
                    ob[(size_t)(mb + r) * 2048 + c * 2 + wh] = f2b(1.f / (1.f + __expf(-v)));
                }
            }
        } else if (EPI == 0) {
#pragma unroll
            for (int i = 0; i < 4; ++i) {
                const int mb = m0 + wr * 64 + i * 16 + r0;
#pragma unroll
                for (int r = 0; r < 4; ++r)
                    ob[(size_t)(mb + r) * N + n] = f2b(acc[i][j][r] + bv);
            }
        } else {
#pragma unroll
            for (int i = 0; i < 4; ++i) {
                const int mb = m0 + wr * 64 + i * 16 + r0;
#pragma unroll
                for (int r = 0; r < 4; ++r)
                    o0[(size_t)(mb + r) * N + n] = acc[i][j][r] + bv;
            }
        }
    }
}

// ---------------- scan (chunked, recompute, 1 channel/thread) ----------------
// S=4096 split into 64 chunks of 64. Streams: b*1024 + c (4096 total).
// grid (64, 4, 4) = 1024 blocks -> 16 waves/CU (latency hiding).
// gxga: interleaved [m][c][2] bf16 (gx, ga). FINAL writes h IN PLACE over xhb.
template<int FINAL>
__global__ void scan_chunk(const ushort2* __restrict__ gxga,
                           ushort* __restrict__ xhb,
                           const float* __restrict__ sp, const float* __restrict__ aim,
                           float2* __restrict__ carryA, float2* __restrict__ carryH,
                           const float2* __restrict__ prefixH,
                           float* __restrict__ hlast) {
    const int c = blockIdx.y * 256 + threadIdx.x;   // channel [0,1024)
    const int b = blockIdx.z;
    const int chunk = blockIdx.x;
    const int m0 = b * 4096 + chunk * 64;
    const float spc = sp[c], amc = aim[c];
    float Ar = 1.f, Ai = 0.f, Hr = 0.f, Hi = 0.f;
    if (FINAL) { float2 p = prefixH[chunk * 4096 + b * 1024 + c]; Hr = p.x; Hi = p.y; }
#pragma unroll 8
    for (int t = 0; t < 64; ++t) {
        const size_t m = (size_t)(m0 + t);
        const ushort2 g = gxga[m * 1024 + c];       // (gx, ga)
        const float xr = b2f(xhb[m * 2048 + c]);
        const float xi = b2f(xhb[m * 2048 + c + 1024]);
        const float gav = b2f(g.y);
        const float er = __expf(-8.f * gav * spc);
        float sn, cs; __sincosf(amc * gav, &sn, &cs);
        const float f = sqrtf(fmaxf(1.f - er * er, 1e-6f)) * b2f(g.x);
        const float ar = er * cs, ai = er * sn;
        const float xcr = f * xr, xci = f * xi;
        const float h2 = ar * Hr - ai * Hi + xcr;
        Hi = ar * Hi + ai * Hr + xci; Hr = h2;
        if (FINAL) {
            xhb[m * 2048 + c] = f2b(Hr);
            xhb[m * 2048 + c + 1024] = f2b(Hi);
        } else {
            const float a2 = ar * Ar - ai * Ai; Ai = ar * Ai + ai * Ar; Ar = a2;
        }
    }
    if (!FINAL) {
        const int s = chunk * 4096 + b * 1024 + c;
        carryA[s] = make_float2(Ar, Ai);
        carryH[s] = make_float2(Hr, Hi);
    } else if (chunk == 63) {
        hlast[b * 2048 + c] = Hr;
        hlast[b * 2048 + c + 1024] = Hi;
    }
}

__global__ void scan_top(const float2* __restrict__ cA, const float2* __restrict__ cH,
                         float2* __restrict__ pH) {
    const int s = blockIdx.x * 256 + threadIdx.x;  // 4096 streams
    float pr = 0.f, pi = 0.f;
    for (int ch = 0; ch < 64; ++ch) {
        pH[ch * 4096 + s] = make_float2(pr, pi);
        float2 A = cA[ch * 4096 + s];
        float2 H = cH[ch * 4096 + s];
        float t = A.x * pr - A.y * pi + H.x;
        pi = A.x * pi + A.y * pr + H.y;
        pr = t;
    }
}

// ws too small: encode ws_size (MB) into y so the bench error reveals it.
__global__ void ws_report_kernel(float* out, float code) {
    out[blockIdx.x * 256 + threadIdx.x] = code;
}

// ---------------- launch ----------------
extern "C" void kernel_launch(void* const* d_in, const int* in_sizes, int n_in,
                              void* d_out, int out_size, void* d_ws, size_t ws_size,
                              hipStream_t stream) {
    const float* x     = (const float*)d_in[0];
    const float* w_in  = (const float*)d_in[1];
    const float* b_in  = (const float*)d_in[2];
    const float* w_gx  = (const float*)d_in[3];
    const float* b_gx  = (const float*)d_in[4];
    const float* w_ga  = (const float*)d_in[5];
    const float* b_ga  = (const float*)d_in[6];
    const float* arp   = (const float*)d_in[7];
    const float* aip   = (const float*)d_in[8];
    const float* w_out = (const float*)d_in[9];
    const float* b_out = (const float*)d_in[10];
    float* out = (float*)d_out;

    // ---- workspace layout (~143 MB, same as last passing round) ----
    char* p = (char*)d_ws;
    ushort* R0    = (ushort*)p; p += 67108864;
    ushort* xb    = R0;                          // 16384x1024 bf16 (phase A)
    ushort* gxga  = R0;                          // 16384x1024x2 bf16 interleaved (phase B)
    ushort* xhb   = (ushort*)p; p += 67108864;   // 16384x2048 bf16, then h_m in place
    ushort* w_inT = (ushort*)p; p += 4194304;    // (2048x1024) K-contig
    ushort* w_outT= (ushort*)p; p += 4194304;    // (1024x2048) K-contig
    ushort* WgT   = (ushort*)p; p += 1048576;    // (2048x256)  K-contig
    float*  bg    = (float*)p;  p += 8192;
    float*  sp    = (float*)p;  p += 4096;
    float2* cA    = (float2*)p; p += 2097152;    // 64 chunks x 4096 streams
    float2* cH    = (float2*)p; p += 2097152;
    float2* pH    = (float2*)p; p += 2097152;
    size_t need = (size_t)(p - (char*)d_ws);
    if (ws_size < need) {
        float code = 1000.0f + (float)(ws_size >> 20);
        ws_report_kernel<<<64, 256, 0, stream>>>(out, code);
        return;
    }

    cvt_x_kernel<<<16384, 256, 0, stream>>>((const float4*)x, (ushort4*)xb);
    // weight transposes (f32 -> bf16, K-contig)
    transpose_cvt<<<dim3(32, 16, 1), 256, 0, stream>>>(w_in, w_inT, 1024, 2048, 1024, 0, 0);
    transpose_cvt<<<dim3(16, 32, 1), 256, 0, stream>>>(w_out, w_outT, 2048, 1024, 2048, 0, 0);
    transpose_cvt<<<dim3(2, 4, 8), 256, 0, stream>>>(w_gx, WgT, 256, 128, 256, 32768, 65536);
    transpose_cvt<<<dim3(2, 4, 8), 256, 0, stream>>>(w_ga, WgT + 32768, 256, 128, 256, 32768, 65536);
    prep_small_kernel<<<8, 256, 0, stream>>>(b_gx, b_ga, arp, bg, sp);

    // xh = x @ w_in + b_in  (store bf16)   2048 blocks, GX=16
    gemm_bt<0><<<2048, 256, 0, stream>>>(xb, w_inT, 16384, 2048, 1024, 1024, 1024, 4,
                                         b_in, nullptr, xhb);
    // gates = sigmoid(blockdiag(xh)) -> interleaved (gx,ga) over R0 (xb dead)   GX=16
    gemm_bt<1><<<2048, 256, 0, stream>>>(xhb, WgT, 16384, 2048, 256, 2048, 256, 4,
                                         bg, nullptr, gxga);
    // scan
    scan_chunk<0><<<dim3(64, 4, 4), 256, 0, stream>>>((const ushort2*)gxga, xhb, sp, aip,
                                                      cA, cH, nullptr, nullptr);
    scan_top<<<16, 256, 0, stream>>>(cA, cH, pH);
    scan_chunk<1><<<dim3(64, 4, 4), 256, 0, stream>>>((const ushort2*)gxga, xhb, sp, aip,
                                                      nullptr, nullptr, pH, out + 16777216);
    // y = h_m @ w_out + b_out   (h_m is xhb, in place)   1024 blocks, GX=8
    gemm_bt<2><<<1024, 256, 0, stream>>>(xhb, w_outT, 16384, 1024, 2048, 2048, 2048, 3,
                                         b_out, out, nullptr);
}

// Round 6
// 413.322 us; speedup vs baseline: 1.0848x; 1.0111x over previous
//
#include <hip/hip_runtime.h>
#include <cstdint>
#include <cstddef>

// ---------------- types & helpers ----------------
typedef short bf16x8 __attribute__((ext_vector_type(8)));
typedef ushort ushort8 __attribute__((ext_vector_type(8)));
typedef float f32x4 __attribute__((ext_vector_type(4)));

__device__ __forceinline__ float b2f(ushort u) {
    union { float f; uint32_t i; } v; v.i = ((uint32_t)u) << 16; return v.f;
}
__device__ __forceinline__ ushort f2b(float f) {
    union { float f; uint32_t i; } v; v.f = f;
    uint32_t r = v.i + 0x7FFFu + ((v.i >> 16) & 1u);
    return (ushort)(r >> 16);
}

#define ASYNC16(g, l) \
    __builtin_amdgcn_global_load_lds((const __attribute__((address_space(1))) void*)(g), \
                                     (__attribute__((address_space(3))) void*)(l), 16, 0, 0)

// ---------------- prep kernels ----------------
__global__ void cvt_x_kernel(const float4* __restrict__ x, ushort4* __restrict__ xb) {
    int i = blockIdx.x * 256 + threadIdx.x;
    float4 v = x[i];
    ushort4 o; o.x = f2b(v.x); o.y = f2b(v.y); o.z = f2b(v.z); o.w = f2b(v.w);
    xb[i] = o;
}

// Tiled f32 -> bf16 transpose: in [R][C] f32 (row-major) -> out [C][R] bf16.
__global__ void transpose_cvt(const float* __restrict__ in, ushort* __restrict__ out,
                              int R, int C, int outStride,
                              size_t inBatch, size_t outBatch) {
    __shared__ float t[64 * 65];
    const int tid = threadIdx.x;
    const int r0 = blockIdx.y * 64, c0 = blockIdx.x * 64;
    const float* inp = in + blockIdx.z * inBatch;
    ushort* outp = out + blockIdx.z * outBatch;

    const int lr = tid >> 4;
    const int lc = (tid & 15) * 4;
#pragma unroll
    for (int i = 0; i < 4; ++i) {
        const int row = lr + i * 16;
        const float4 v = *(const float4*)&inp[(size_t)(r0 + row) * C + c0 + lc];
        t[row * 65 + lc + 0] = v.x;
        t[row * 65 + lc + 1] = v.y;
        t[row * 65 + lc + 2] = v.z;
        t[row * 65 + lc + 3] = v.w;
    }
    __syncthreads();
    const int oc = tid >> 2;
    const int orr = (tid & 3) * 16;
    ushort8 a, b;
#pragma unroll
    for (int i = 0; i < 8; ++i) a[i] = f2b(t[(orr + i) * 65 + oc]);
#pragma unroll
    for (int i = 0; i < 8; ++i) b[i] = f2b(t[(orr + 8 + i) * 65 + oc]);
    ushort* dst = outp + (size_t)(c0 + oc) * outStride + r0 + orr;
    *(ushort8*)dst = a;
    *(ushort8*)(dst + 8) = b;
}

__global__ void prep_small_kernel(const float* __restrict__ b_gx, const float* __restrict__ b_ga,
                                  const float* __restrict__ arp,
                                  float* __restrict__ bg, float* __restrict__ sp) {
    int idx = blockIdx.x * 256 + threadIdx.x;
    {
        int nb = idx >> 8, r = idx & 255;
        bg[idx] = (r < 128) ? b_gx[nb * 128 + r] : b_ga[nb * 128 + r - 128];
    }
    if (idx < 1024) sp[idx] = log1pf(__expf(arp[idx]));
}

// ---------------- 256x256 counted-vmcnt MFMA GEMM (C = A @ B^T + bias) ----------------
// 512 threads / 8 waves (2M x 4N). BK=32, 4-deep LDS ring (128 KB), stage t+3
// while computing t, vmcnt(8) steady state (never 0), raw s_barrier 1x/K-tile.
// LDS XOR swizzle: linear gload_lds dest + inverse-swizzled global SOURCE;
// frag reads apply the same involution (kchunk ^= (row>>1)&3).
// EPI 0: bf16 store to ob. EPI 2: f32 store to o0.
template<int EPI>
__launch_bounds__(512, 1)
__global__ void gemm256(const ushort* __restrict__ A, const ushort* __restrict__ B,
                        int M, int N, int K, int lda, int ldb, int gxbits,
                        const float* __restrict__ bias,
                        float* __restrict__ o0, ushort* __restrict__ ob) {
    __shared__ ushort lds[4 * 16384];   // 128 KB: ring of 4 x (A 8192 | B 8192)
    const int tid = threadIdx.x;
    const int lane = tid & 63;
    const int wave = tid >> 6;
    const int wr = wave >> 2;           // 0..1  (M half)
    const int wc = wave & 3;            // 0..3  (N quarter)

    // XCD bijective swizzle (gridDim.x % 8 == 0)
    const int swz = (blockIdx.x & 7) * (gridDim.x >> 3) + (blockIdx.x >> 3);
    const int m0 = (swz >> gxbits) * 256;
    const int n0 = (swz & ((1 << gxbits) - 1)) * 256;

    // staging source (per-lane, swizzled k-chunk)
    const int rA = tid >> 2;                          // 0..127
    const int cA = (tid & 3) ^ ((rA >> 1) & 3);       // swizzled 16B k-chunk
    const char* aSrc0 = (const char*)A + 2 * ((size_t)(m0 + rA) * lda + cA * 8);
    const char* aSrc1 = aSrc0 + 2 * (size_t)128 * lda;
    const char* bSrc0 = (const char*)B + 2 * ((size_t)(n0 + rA) * ldb + cA * 8);
    const char* bSrc1 = bSrc0 + 2 * (size_t)128 * ldb;

    f32x4 acc[8][4];
#pragma unroll
    for (int i = 0; i < 8; ++i)
#pragma unroll
        for (int j = 0; j < 4; ++j) acc[i][j] = (f32x4){0.f, 0.f, 0.f, 0.f};

    // frag read bases (ushort offsets within a buffer)
    const int fphys = (lane >> 4) ^ (((lane & 15) >> 1) & 3);
    const int baseA = (wr * 128 + (lane & 15)) * 32 + fphys * 8;
    const int baseB = 8192 + (wc * 64 + (lane & 15)) * 32 + fphys * 8;

    const int nt = K >> 5;

#define STAGE256(t) do {                                               \
        ushort* buf = lds + ((t) & 3) * 16384;                         \
        const size_t o = (size_t)(t) * 64;                             \
        ASYNC16(aSrc0 + o, buf + tid * 8);                             \
        ASYNC16(aSrc1 + o, buf + tid * 8 + 4096);                      \
        ASYNC16(bSrc0 + o, buf + 8192 + tid * 8);                      \
        ASYNC16(bSrc1 + o, buf + 8192 + tid * 8 + 4096);               \
    } while (0)

    STAGE256(0); STAGE256(1); STAGE256(2);
    asm volatile("s_waitcnt vmcnt(8)" ::: "memory");   // tile 0 resident
    __builtin_amdgcn_s_barrier();
    __builtin_amdgcn_sched_barrier(0);

    for (int t = 0; t < nt; ++t) {
        const int rem = nt - 1 - t;
        if (rem >= 3) STAGE256(t + 3);
        const ushort* buf = lds + (t & 3) * 16384;
        bf16x8 af[8], bf[4];
#pragma unroll
        for (int mf = 0; mf < 8; ++mf) af[mf] = *(const bf16x8*)(buf + baseA + mf * 512);
#pragma unroll
        for (int nf = 0; nf < 4; ++nf) bf[nf] = *(const bf16x8*)(buf + baseB + nf * 512);
        __builtin_amdgcn_s_setprio(1);
#pragma unroll
        for (int mf = 0; mf < 8; ++mf)
#pragma unroll
            for (int nf = 0; nf < 4; ++nf)
                acc[mf][nf] = __builtin_amdgcn_mfma_f32_16x16x32_bf16(af[mf], bf[nf], acc[mf][nf], 0, 0, 0);
        __builtin_amdgcn_s_setprio(0);
        if (rem > 0) {
            if (rem >= 3)      asm volatile("s_waitcnt vmcnt(8)" ::: "memory");
            else if (rem == 2) asm volatile("s_waitcnt vmcnt(4)" ::: "memory");
            else               asm volatile("s_waitcnt vmcnt(0)" ::: "memory");
            __builtin_amdgcn_s_barrier();
            __builtin_amdgcn_sched_barrier(0);
        }
    }
#undef STAGE256

    // epilogue: row = m0 + wr*128 + mf*16 + (lane>>4)*4 + r; col = n0 + wc*64 + nf*16 + (lane&15)
    const int r0 = (lane >> 4) * 4;
    const int cn = lane & 15;
#pragma unroll
    for (int nf = 0; nf < 4; ++nf) {
        const int col = n0 + wc * 64 + nf * 16 + cn;
        const float bv = bias[col];
#pragma unroll
        for (int mf = 0; mf < 8; ++mf) {
            const int rowb = m0 + wr * 128 + mf * 16 + r0;
#pragma unroll
            for (int r = 0; r < 4; ++r) {
                const float v = acc[mf][nf][r] + bv;
                if (EPI == 0) ob[(size_t)(rowb + r) * N + col] = f2b(v);
                else          o0[(size_t)(rowb + r) * N + col] = v;
            }
        }
    }
}

// ---------------- 128x128 MFMA GEMM (gate only: EPI 1) ----------------
template<int EPI>
__launch_bounds__(256, 2)
__global__ void gemm_bt(const ushort* __restrict__ A, const ushort* __restrict__ B,
                        int M, int N, int K, int lda, int ldb, int gxbits,
                        const float* __restrict__ bias,
                        float* __restrict__ o0,
                        ushort* __restrict__ ob) {
    __shared__ ushort At[128 * 32];
    __shared__ ushort Bt[128 * 32];
    const int tid = threadIdx.x;
    const int lane = tid & 63;
    const int wave = tid >> 6;
    const int wr = wave >> 1, wc = wave & 1;

    const int swz = (blockIdx.x & 7) * (gridDim.x >> 3) + (blockIdx.x >> 3);
    const int m0 = (swz >> gxbits) * 128;
    const int n0 = (swz & ((1 << gxbits) - 1)) * 128;

    const ushort* Ab = A;
    if (EPI == 1) Ab += (size_t)(n0 >> 8) * 256;  // block-diagonal: A column offset

    const int arow = tid >> 2;
    const int acolb = (tid & 3) << 4;
    const char* ag0 = (const char*)Ab + ((size_t)(m0 + arow) * lda) * 2 + acolb;
    const char* ag1 = ag0 + (size_t)64 * lda * 2;
    const char* bgp0 = (const char*)B + ((size_t)(n0 + arow) * ldb) * 2 + acolb;
    const char* bgp1 = bgp0 + (size_t)64 * ldb * 2;
    ushort* la0 = At + tid * 8; ushort* la1 = la0 + 2048;
    ushort* lb0 = Bt + tid * 8; ushort* lb1 = lb0 + 2048;

    f32x4 acc[4][4];
#pragma unroll
    for (int i = 0; i < 4; ++i)
#pragma unroll
        for (int j = 0; j < 4; ++j) acc[i][j] = (f32x4){0.f, 0.f, 0.f, 0.f};

    const int fm = lane & 15;
    const int fko = (lane >> 4) * 8;
    const ushort* Af = At + (wr * 64 + fm) * 32 + fko;
    const ushort* Bf = Bt + (wc * 64 + fm) * 32 + fko;

    const int nk = K >> 5;
    for (int kk = 0; kk < nk; ++kk) {
        __syncthreads();
        const size_t off = (size_t)kk * 64;
        ASYNC16(ag0 + off, la0);
        ASYNC16(ag1 + off, la1);
        ASYNC16(bgp0 + off, lb0);
        ASYNC16(bgp1 + off, lb1);
        __syncthreads();
        bf16x8 af[4], bfv[4];
#pragma unroll
        for (int i = 0; i < 4; ++i) af[i]  = *(const bf16x8*)(Af + i * 512);
#pragma unroll
        for (int i = 0; i < 4; ++i) bfv[i] = *(const bf16x8*)(Bf + i * 512);
#pragma unroll
        for (int i = 0; i < 4; ++i)
#pragma unroll
            for (int j = 0; j < 4; ++j)
                acc[i][j] = __builtin_amdgcn_mfma_f32_16x16x32_bf16(af[i], bfv[j], acc[i][j], 0, 0, 0);
    }

    const int r0 = (lane >> 4) * 4;
    const int cn = lane & 15;
#pragma unroll
    for (int j = 0; j < 4; ++j) {
        const int n = n0 + wc * 64 + j * 16 + cn;
        const float bv = bias[n];
        if (EPI == 1) {
            const int nb = n >> 8, rr = n & 255;
            const int c = nb * 128 + (rr & 127);
            const int wh = (rr >> 7) & 1;      // 0 = gx, 1 = ga
#pragma unroll
            for (int i = 0; i < 4; ++i) {
                const int mb = m0 + wr * 64 + i * 16 + r0;
#pragma unroll
                for (int r = 0; r < 4; ++r) {
                    float v = acc[i][j][r] + bv;
                    ob[(size_t)(mb + r) * 2048 + c * 2 + wh] = f2b(1.f / (1.f + __expf(-v)));
                }
            }
        } else {
#pragma unroll
            for (int i = 0; i < 4; ++i) {
                const int mb = m0 + wr * 64 + i * 16 + r0;
#pragma unroll
                for (int r = 0; r < 4; ++r)
                    o0[(size_t)(mb + r) * N + n] = acc[i][j][r] + bv;
            }
        }
    }
}

// ---------------- scan (chunked, recompute, 1 channel/thread) ----------------
template<int FINAL>
__global__ void scan_chunk(const ushort2* __restrict__ gxga,
                           ushort* __restrict__ xhb,
                           const float* __restrict__ sp, const float* __restrict__ aim,
                           float2* __restrict__ carryA, float2* __restrict__ carryH,
                           const float2* __restrict__ prefixH,
                           float* __restrict__ hlast) {
    const int c = blockIdx.y * 256 + threadIdx.x;   // channel [0,1024)
    const int b = blockIdx.z;
    const int chunk = blockIdx.x;
    const int m0 = b * 4096 + chunk * 64;
    const float spc = sp[c], amc = aim[c];
    float Ar = 1.f, Ai = 0.f, Hr = 0.f, Hi = 0.f;
    if (FINAL) { float2 p = prefixH[chunk * 4096 + b * 1024 + c]; Hr = p.x; Hi = p.y; }
#pragma unroll 8
    for (int t = 0; t < 64; ++t) {
        const size_t m = (size_t)(m0 + t);
        const ushort2 g = gxga[m * 1024 + c];       // (gx, ga)
        const float xr = b2f(xhb[m * 2048 + c]);
        const float xi = b2f(xhb[m * 2048 + c + 1024]);
        const float gav = b2f(g.y);
        const float er = __expf(-8.f * gav * spc);
        float sn, cs; __sincosf(amc * gav, &sn, &cs);
        const float f = sqrtf(fmaxf(1.f - er * er, 1e-6f)) * b2f(g.x);
        const float ar = er * cs, ai = er * sn;
        const float xcr = f * xr, xci = f * xi;
        const float h2 = ar * Hr - ai * Hi + xcr;
        Hi = ar * Hi + ai * Hr + xci; Hr = h2;
        if (FINAL) {
            xhb[m * 2048 + c] = f2b(Hr);
            xhb[m * 2048 + c + 1024] = f2b(Hi);
        } else {
            const float a2 = ar * Ar - ai * Ai; Ai = ar * Ai + ai * Ar; Ar = a2;
        }
    }
    if (!FINAL) {
        const int s = chunk * 4096 + b * 1024 + c;
        carryA[s] = make_float2(Ar, Ai);
        carryH[s] = make_float2(Hr, Hi);
    } else if (chunk == 63) {
        hlast[b * 2048 + c] = Hr;
        hlast[b * 2048 + c + 1024] = Hi;
    }
}

__global__ void scan_top(const float2* __restrict__ cA, const float2* __restrict__ cH,
                         float2* __restrict__ pH) {
    const int s = blockIdx.x * 256 + threadIdx.x;  // 4096 streams
    float pr = 0.f, pi = 0.f;
    for (int ch = 0; ch < 64; ++ch) {
        pH[ch * 4096 + s] = make_float2(pr, pi);
        float2 A = cA[ch * 4096 + s];
        float2 H = cH[ch * 4096 + s];
        float t = A.x * pr - A.y * pi + H.x;
        pi = A.x * pi + A.y * pr + H.y;
        pr = t;
    }
}

__global__ void ws_report_kernel(float* out, float code) {
    out[blockIdx.x * 256 + threadIdx.x] = code;
}

// ---------------- launch ----------------
extern "C" void kernel_launch(void* const* d_in, const int* in_sizes, int n_in,
                              void* d_out, int out_size, void* d_ws, size_t ws_size,
                              hipStream_t stream) {
    const float* x     = (const float*)d_in[0];
    const float* w_in  = (const float*)d_in[1];
    const float* b_in  = (const float*)d_in[2];
    const float* w_gx  = (const float*)d_in[3];
    const float* b_gx  = (const float*)d_in[4];
    const float* w_ga  = (const float*)d_in[5];
    const float* b_ga  = (const float*)d_in[6];
    const float* arp   = (const float*)d_in[7];
    const float* aip   = (const float*)d_in[8];
    const float* w_out = (const float*)d_in[9];
    const float* b_out = (const float*)d_in[10];
    float* out = (float*)d_out;

    // ---- workspace layout (~143 MB) ----
    char* p = (char*)d_ws;
    ushort* R0    = (ushort*)p; p += 67108864;
    ushort* xb    = R0;                          // 16384x1024 bf16 (phase A)
    ushort* gxga  = R0;                          // 16384x1024x2 bf16 interleaved (phase B)
    ushort* xhb   = (ushort*)p; p += 67108864;   // 16384x2048 bf16, then h_m in place
    ushort* w_inT = (ushort*)p; p += 4194304;
    ushort* w_outT= (ushort*)p; p += 4194304;
    ushort* WgT   = (ushort*)p; p += 1048576;
    float*  bg    = (float*)p;  p += 8192;
    float*  sp    = (float*)p;  p += 4096;
    float2* cA    = (float2*)p; p += 2097152;
    float2* cH    = (float2*)p; p += 2097152;
    float2* pH    = (float2*)p; p += 2097152;
    size_t need = (size_t)(p - (char*)d_ws);
    if (ws_size < need) {
        float code = 1000.0f + (float)(ws_size >> 20);
        ws_report_kernel<<<64, 256, 0, stream>>>(out, code);
        return;
    }

    cvt_x_kernel<<<16384, 256, 0, stream>>>((const float4*)x, (ushort4*)xb);
    transpose_cvt<<<dim3(32, 16, 1), 256, 0, stream>>>(w_in, w_inT, 1024, 2048, 1024, 0, 0);
    transpose_cvt<<<dim3(16, 32, 1), 256, 0, stream>>>(w_out, w_outT, 2048, 1024, 2048, 0, 0);
    transpose_cvt<<<dim3(2, 4, 8), 256, 0, stream>>>(w_gx, WgT, 256, 128, 256, 32768, 65536);
    transpose_cvt<<<dim3(2, 4, 8), 256, 0, stream>>>(w_ga, WgT + 32768, 256, 128, 256, 32768, 65536);
    prep_small_kernel<<<8, 256, 0, stream>>>(b_gx, b_ga, arp, bg, sp);

    // xh = x @ w_in + b_in  (bf16)   tiles 64x8 = 512 blocks, GX=8
    gemm256<0><<<512, 512, 0, stream>>>(xb, w_inT, 16384, 2048, 1024, 1024, 1024, 3,
                                        b_in, nullptr, xhb);
    // gates = sigmoid(blockdiag(xh)) -> interleaved (gx,ga) over R0   GX=16
    gemm_bt<1><<<2048, 256, 0, stream>>>(xhb, WgT, 16384, 2048, 256, 2048, 256, 4,
                                         bg, nullptr, gxga);
    // scan
    scan_chunk<0><<<dim3(64, 4, 4), 256, 0, stream>>>((const ushort2*)gxga, xhb, sp, aip,
                                                      cA, cH, nullptr, nullptr);
    scan_top<<<16, 256, 0, stream>>>(cA, cH, pH);
    scan_chunk<1><<<dim3(64, 4, 4), 256, 0, stream>>>((const ushort2*)gxga, xhb, sp, aip,
                                                      nullptr, nullptr, pH, out + 16777216);
    // y = h_m @ w_out + b_out   tiles 64x4 = 256 blocks, GX=4 -> gxbits=2
    gemm256<2><<<256, 512, 0, stream>>>(xhb, w_outT, 16384, 1024, 2048, 2048, 2048, 2,
                                        b_out, out, nullptr);
}

// Round 9
// 406.015 us; speedup vs baseline: 1.1043x; 1.0180x over previous
//
#include <hip/hip_runtime.h>
#include <cstdint>
#include <cstddef>

// ---------------- types & helpers ----------------
typedef short bf16x8 __attribute__((ext_vector_type(8)));
typedef ushort ushort8 __attribute__((ext_vector_type(8)));
typedef float f32x4 __attribute__((ext_vector_type(4)));

__device__ __forceinline__ float b2f(ushort u) {
    union { float f; uint32_t i; } v; v.i = ((uint32_t)u) << 16; return v.f;
}
__device__ __forceinline__ ushort f2b(float f) {
    union { float f; uint32_t i; } v; v.f = f;
    uint32_t r = v.i + 0x7FFFu + ((v.i >> 16) & 1u);
    return (ushort)(r >> 16);
}

#define ASYNC16(g, l) \
    __builtin_amdgcn_global_load_lds((const __attribute__((address_space(1))) void*)(g), \
                                     (__attribute__((address_space(3))) void*)(l), 16, 0, 0)

// ---------------- prep kernels ----------------
__global__ void cvt_x_kernel(const float4* __restrict__ x, ushort4* __restrict__ xb) {
    int i = blockIdx.x * 256 + threadIdx.x;
    float4 v = x[i];
    ushort4 o; o.x = f2b(v.x); o.y = f2b(v.y); o.z = f2b(v.z); o.w = f2b(v.w);
    xb[i] = o;
}

// Tiled f32 -> bf16 transpose: in [R][C] f32 (row-major) -> out [C][R] bf16.
__global__ void transpose_cvt(const float* __restrict__ in, ushort* __restrict__ out,
                              int R, int C, int outStride,
                              size_t inBatch, size_t outBatch) {
    __shared__ float t[64 * 65];
    const int tid = threadIdx.x;
    const int r0 = blockIdx.y * 64, c0 = blockIdx.x * 64;
    const float* inp = in + blockIdx.z * inBatch;
    ushort* outp = out + blockIdx.z * outBatch;

    const int lr = tid >> 4;
    const int lc = (tid & 15) * 4;
#pragma unroll
    for (int i = 0; i < 4; ++i) {
        const int row = lr + i * 16;
        const float4 v = *(const float4*)&inp[(size_t)(r0 + row) * C + c0 + lc];
        t[row * 65 + lc + 0] = v.x;
        t[row * 65 + lc + 1] = v.y;
        t[row * 65 + lc + 2] = v.z;
        t[row * 65 + lc + 3] = v.w;
    }
    __syncthreads();
    const int oc = tid >> 2;
    const int orr = (tid & 3) * 16;
    ushort8 a, b;
#pragma unroll
    for (int i = 0; i < 8; ++i) a[i] = f2b(t[(orr + i) * 65 + oc]);
#pragma unroll
    for (int i = 0; i < 8; ++i) b[i] = f2b(t[(orr + 8 + i) * 65 + oc]);
    ushort* dst = outp + (size_t)(c0 + oc) * outStride + r0 + orr;
    *(ushort8*)dst = a;
    *(ushort8*)(dst + 8) = b;
}

__global__ void prep_small_kernel(const float* __restrict__ b_gx, const float* __restrict__ b_ga,
                                  const float* __restrict__ arp,
                                  float* __restrict__ bg, float* __restrict__ sp) {
    int idx = blockIdx.x * 256 + threadIdx.x;
    {
        int nb = idx >> 8, r = idx & 255;
        bg[idx] = (r < 128) ? b_gx[nb * 128 + r] : b_ga[nb * 128 + r - 128];
    }
    if (idx < 1024) sp[idx] = log1pf(__expf(arp[idx]));
}

// ---------------- 256x256 8-phase MFMA GEMM (C = A @ B^T + bias) ----------------
// 512 threads / 8 waves (2M x 4N), per-wave 128x64 output. BK=64.
// LDS 128 KB = 2 buffers x (A 32KB | B 32KB); half-tiles (128 rows x 64 k) staged
// one per phase; counted vmcnt(4) at phases 4 & 8 only (2 half-tiles in flight).
// XOR swizzle chunk^=(row&7) applied on stage SOURCE and frag read (involution).
// EPI 0: bf16 store to ob. EPI 2: f32 store to o0.
#define MFMA1(a_, x_, y_) a_ = __builtin_amdgcn_mfma_f32_16x16x32_bf16(x_, y_, a_, 0, 0, 0)
#define VM4() asm volatile("s_waitcnt vmcnt(4)" ::: "memory")
#define VM0() asm volatile("s_waitcnt vmcnt(0)" ::: "memory")
#define PRE() do { __builtin_amdgcn_s_barrier(); \
    asm volatile("s_waitcnt lgkmcnt(0)" ::: "memory"); \
    __builtin_amdgcn_sched_barrier(0); __builtin_amdgcn_s_setprio(1); } while (0)
#define POST() do { __builtin_amdgcn_s_setprio(0); __builtin_amdgcn_s_barrier(); \
    __builtin_amdgcn_sched_barrier(0); } while (0)

template<int EPI>
__launch_bounds__(512, 1)
__global__ void gemm8p(const ushort* __restrict__ A, const ushort* __restrict__ B,
                       int M, int N, int K, int lda, int ldb, int gxbits,
                       const float* __restrict__ bias,
                       float* __restrict__ o0, ushort* __restrict__ ob) {
    __shared__ ushort lds[65536];   // 128 KB
    const int tid = threadIdx.x;
    const int lane = tid & 63;
    const int wave = tid >> 6;
    const int wr = wave >> 2;       // 0..1
    const int wc = wave & 3;        // 0..3

    const int swz = (blockIdx.x & 7) * (gridDim.x >> 3) + (blockIdx.x >> 3);
    const int m0 = (swz >> gxbits) * 256;
    const int n0 = (swz & ((1 << gxbits) - 1)) * 256;

    // staging: one load = 512 thr x 16B = 64 rows x 128B. row=tid>>3, phys chunk=tid&7,
    // logical (global) chunk = (tid&7) ^ (row&7).
    const int srow = tid >> 3;
    const int schk = (tid & 7) ^ (srow & 7);
    const char* aS = (const char*)A + 2 * ((size_t)(m0 + srow) * lda) + schk * 16;
    const char* bS = (const char*)B + 2 * ((size_t)(n0 + srow) * ldb) + schk * 16;
    const size_t astep = (size_t)64 * lda * 2;
    const size_t bstep = (size_t)64 * ldb * 2;

#define STG_A0(t) do { size_t cb = (size_t)(t) * 128; ushort* d = lds + ((t) & 1) * 32768; \
        ASYNC16(aS + cb, d + tid * 8); ASYNC16(aS + astep + cb, d + 4096 + tid * 8); } while (0)
#define STG_A1(t) do { size_t cb = (size_t)(t) * 128; ushort* d = lds + ((t) & 1) * 32768 + 8192; \
        ASYNC16(aS + 2 * astep + cb, d + tid * 8); ASYNC16(aS + 3 * astep + cb, d + 4096 + tid * 8); } while (0)
#define STG_B0(t) do { size_t cb = (size_t)(t) * 128; ushort* d = lds + ((t) & 1) * 32768 + 16384; \
        ASYNC16(bS + cb, d + tid * 8); ASYNC16(bS + bstep + cb, d + 4096 + tid * 8); } while (0)
#define STG_B1(t) do { size_t cb = (size_t)(t) * 128; ushort* d = lds + ((t) & 1) * 32768 + 24576; \
        ASYNC16(bS + 2 * bstep + cb, d + tid * 8); ASYNC16(bS + 3 * bstep + cb, d + 4096 + tid * 8); } while (0)

    f32x4 acc[8][4];
#pragma unroll
    for (int i = 0; i < 8; ++i)
#pragma unroll
        for (int j = 0; j < 4; ++j) acc[i][j] = (f32x4){0.f, 0.f, 0.f, 0.f};

    // frag addressing (ushort offsets). row stride 64 ushorts (128B).
    // phys chunk = (kk*4 + lane>>4) ^ (lane&7)  [row&7 == lane&7 for all frag rows]
    const int cph0 = (((lane >> 4)) ^ (lane & 7)) * 8;
    const int cph1 = (((lane >> 4) + 4) ^ (lane & 7)) * 8;
    const int aRB = (wr * 128 + (lane & 15)) * 64;
    const int bRB = 16384 + (wc * 64 + (lane & 15)) * 64;

    bf16x8 aa[8], p0, p1, p2, p3, q0, q1, q2, q3;

#define LDA(bb, mfb) do { _Pragma("unroll") \
    for (int i_ = 0; i_ < 4; ++i_) { \
        aa[2 * i_]     = *(const bf16x8*)(lds + (bb) + aRB + ((mfb) + i_) * 1024 + cph0); \
        aa[2 * i_ + 1] = *(const bf16x8*)(lds + (bb) + aRB + ((mfb) + i_) * 1024 + cph1); \
    } } while (0)
#define LDP(bb) do { \
        p0 = *(const bf16x8*)(lds + (bb) + bRB + cph0); \
        p1 = *(const bf16x8*)(lds + (bb) + bRB + cph1); \
        p2 = *(const bf16x8*)(lds + (bb) + bRB + 1024 + cph0); \
        p3 = *(const bf16x8*)(lds + (bb) + bRB + 1024 + cph1); } while (0)
#define LDQ(bb) do { \
        q0 = *(const bf16x8*)(lds + (bb) + bRB + 2048 + cph0); \
        q1 = *(const bf16x8*)(lds + (bb) + bRB + 2048 + cph1); \
        q2 = *(const bf16x8*)(lds + (bb) + bRB + 3072 + cph0); \
        q3 = *(const bf16x8*)(lds + (bb) + bRB + 3072 + cph1); } while (0)
#define MMAP(mfb) do { _Pragma("unroll") \
    for (int i_ = 0; i_ < 4; ++i_) { const int m_ = (mfb) + i_; \
        MFMA1(acc[m_][0], aa[2 * i_], p0); MFMA1(acc[m_][0], aa[2 * i_ + 1], p1); \
        MFMA1(acc[m_][1], aa[2 * i_], p2); MFMA1(acc[m_][1], aa[2 * i_ + 1], p3); \
    } } while (0)
#define MMAQ(mfb) do { _Pragma("unroll") \
    for (int i_ = 0; i_ < 4; ++i_) { const int m_ = (mfb) + i_; \
        MFMA1(acc[m_][2], aa[2 * i_], q0); MFMA1(acc[m_][2], aa[2 * i_ + 1], q1); \
        MFMA1(acc[m_][3], aa[2 * i_], q2); MFMA1(acc[m_][3], aa[2 * i_ + 1], q3); \
    } } while (0)

    const int nt = K >> 6;          // K-tiles of 64 (even: 16 or 32)
    // prologue: tile0 all 4 halves + tile1 A halves; wait tile0 resident
    STG_A0(0); STG_A1(0); STG_B0(0); STG_B1(0);
    STG_A0(1); STG_A1(1);
    VM4();
    __builtin_amdgcn_s_barrier();
    __builtin_amdgcn_sched_barrier(0);

    for (int it = 0; it < (nt >> 1); ++it) {
        const int t0 = 2 * it;
        const bool nl = (t0 + 2 < nt);
        // ---- tile t0 (buffer 0) ----
        LDA(0, 0); LDP(0);                 // 12 ds_reads
        STG_B0(t0 + 1);
        PRE(); MMAP(0); POST();            // P1
        LDQ(0);                            // 4
        STG_B1(t0 + 1);
        PRE(); MMAQ(0); POST();            // P2
        LDA(0, 4);                         // 8
        if (nl) STG_A0(t0 + 2);
        PRE(); MMAQ(4); POST();            // P3
        if (nl) { STG_A1(t0 + 2); VM4(); } else VM0();
        PRE(); MMAP(4); POST();            // P4
        // ---- tile t0+1 (buffer 1) ----
        LDA(32768, 0); LDP(32768);
        if (nl) STG_B0(t0 + 2);
        PRE(); MMAP(0); POST();            // P5
        LDQ(32768);
        if (nl) STG_B1(t0 + 2);
        PRE(); MMAQ(0); POST();            // P6
        LDA(32768, 4);
        if (nl) STG_A0(t0 + 3);
        PRE(); MMAQ(4); POST();            // P7
        if (nl) { STG_A1(t0 + 3); VM4(); } else VM0();
        PRE(); MMAP(4); POST();            // P8
    }

    // epilogue: row = m0 + wr*128 + mf*16 + (lane>>4)*4 + r; col = n0 + wc*64 + nf*16 + (lane&15)
    const int r0 = (lane >> 4) * 4;
    const int cn = lane & 15;
#pragma unroll
    for (int nf = 0; nf < 4; ++nf) {
        const int col = n0 + wc * 64 + nf * 16 + cn;
        const float bv = bias[col];
#pragma unroll
        for (int mf = 0; mf < 8; ++mf) {
            const int rowb = m0 + wr * 128 + mf * 16 + r0;
#pragma unroll
            for (int r = 0; r < 4; ++r) {
                const float v = acc[mf][nf][r] + bv;
                if (EPI == 0) ob[(size_t)(rowb + r) * N + col] = f2b(v);
                else          o0[(size_t)(rowb + r) * N + col] = v;
            }
        }
    }
#undef STG_A0
#undef STG_A1
#undef STG_B0
#undef STG_B1
#undef LDA
#undef LDP
#undef LDQ
#undef MMAP
#undef MMAQ
}

// ---------------- 128x128 MFMA GEMM (gate only: EPI 1) ----------------
template<int EPI>
__launch_bounds__(256, 2)
__global__ void gemm_bt(const ushort* __restrict__ A, const ushort* __restrict__ B,
                        int M, int N, int K, int lda, int ldb, int gxbits,
                        const float* __restrict__ bias,
                        float* __restrict__ o0,
                        ushort* __restrict__ ob) {
    __shared__ ushort At[128 * 32];
    __shared__ ushort Bt[128 * 32];
    const int tid = threadIdx.x;
    const int lane = tid & 63;
    const int wave = tid >> 6;
    const int wr = wave >> 1, wc = wave & 1;

    const int swz = (blockIdx.x & 7) * (gridDim.x >> 3) + (blockIdx.x >> 3);
    const int m0 = (swz >> gxbits) * 128;
    const int n0 = (swz & ((1 << gxbits) - 1)) * 128;

    const ushort* Ab = A;
    if (EPI == 1) Ab += (size_t)(n0 >> 8) * 256;  // block-diagonal: A column offset

    const int arow = tid >> 2;
    const int acolb = (tid & 3) << 4;
    const char* ag0 = (const char*)Ab + ((size_t)(m0 + arow) * lda) * 2 + acolb;
    const char* ag1 = ag0 + (size_t)64 * lda * 2;
    const char* bgp0 = (const char*)B + ((size_t)(n0 + arow) * ldb) * 2 + acolb;
    const char* bgp1 = bgp0 + (size_t)64 * ldb * 2;
    ushort* la0 = At + tid * 8; ushort* la1 = la0 + 2048;
    ushort* lb0 = Bt + tid * 8; ushort* lb1 = lb0 + 2048;

    f32x4 acc[4][4];
#pragma unroll
    for (int i = 0; i < 4; ++i)
#pragma unroll
        for (int j = 0; j < 4; ++j) acc[i][j] = (f32x4){0.f, 0.f, 0.f, 0.f};

    const int fm = lane & 15;
    const int fko = (lane >> 4) * 8;
    const ushort* Af = At + (wr * 64 + fm) * 32 + fko;
    const ushort* Bf = Bt + (wc * 64 + fm) * 32 + fko;

    const int nk = K >> 5;
    for (int kk = 0; kk < nk; ++kk) {
        __syncthreads();
        const size_t off = (size_t)kk * 64;
        ASYNC16(ag0 + off, la0);
        ASYNC16(ag1 + off, la1);
        ASYNC16(bgp0 + off, lb0);
        ASYNC16(bgp1 + off, lb1);
        __syncthreads();
        bf16x8 af[4], bfv[4];
#pragma unroll
        for (int i = 0; i < 4; ++i) af[i]  = *(const bf16x8*)(Af + i * 512);
#pragma unroll
        for (int i = 0; i < 4; ++i) bfv[i] = *(const bf16x8*)(Bf + i * 512);
#pragma unroll
        for (int i = 0; i < 4; ++i)
#pragma unroll
            for (int j = 0; j < 4; ++j)
                acc[i][j] = __builtin_amdgcn_mfma_f32_16x16x32_bf16(af[i], bfv[j], acc[i][j], 0, 0, 0);
    }

    const int r0 = (lane >> 4) * 4;
    const int cn = lane & 15;
#pragma unroll
    for (int j = 0; j < 4; ++j) {
        const int n = n0 + wc * 64 + j * 16 + cn;
        const float bv = bias[n];
        if (EPI == 1) {
            const int nb = n >> 8, rr = n & 255;
            const int c = nb * 128 + (rr & 127);
            const int wh = (rr >> 7) & 1;      // 0 = gx, 1 = ga
#pragma unroll
            for (int i = 0; i < 4; ++i) {
                const int mb = m0 + wr * 64 + i * 16 + r0;
#pragma unroll
                for (int r = 0; r < 4; ++r) {
                    float v = acc[i][j][r] + bv;
                    ob[(size_t)(mb + r) * 2048 + c * 2 + wh] = f2b(1.f / (1.f + __expf(-v)));
                }
            }
        } else {
#pragma unroll
            for (int i = 0; i < 4; ++i) {
                const int mb = m0 + wr * 64 + i * 16 + r0;
#pragma unroll
                for (int r = 0; r < 4; ++r)
                    o0[(size_t)(mb + r) * N + n] = acc[i][j][r] + bv;
            }
        }
    }
}

// ---------------- scan (chunked, recompute, 1 channel/thread) ----------------
template<int FINAL>
__global__ void scan_chunk(const ushort2* __restrict__ gxga,
                           ushort* __restrict__ xhb,
                           const float* __restrict__ sp, const float* __restrict__ aim,
                           float2* __restrict__ carryA, float2* __restrict__ carryH,
                           const float2* __restrict__ prefixH,
                           float* __restrict__ hlast) {
    const int c = blockIdx.y * 256 + threadIdx.x;   // channel [0,1024)
    const int b = blockIdx.z;
    const int chunk = blockIdx.x;
    const int m0 = b * 4096 + chunk * 64;
    const float spc = sp[c], amc = aim[c];
    float Ar = 1.f, Ai = 0.f, Hr = 0.f, Hi = 0.f;
    if (FINAL) { float2 p = prefixH[chunk * 4096 + b * 1024 + c]; Hr = p.x; Hi = p.y; }
#pragma unroll 8
    for (int t = 0; t < 64; ++t) {
        const size_t m = (size_t)(m0 + t);
        const ushort2 g = gxga[m * 1024 + c];       // (gx, ga)
        const float xr = b2f(xhb[m * 2048 + c]);
        const float xi = b2f(xhb[m * 2048 + c + 1024]);
        const float gav = b2f(g.y);
        const float er = __expf(-8.f * gav * spc);
        float sn, cs; __sincosf(amc * gav, &sn, &cs);
        const float f = sqrtf(fmaxf(1.f - er * er, 1e-6f)) * b2f(g.x);
        const float ar = er * cs, ai = er * sn;
        const float xcr = f * xr, xci = f * xi;
        const float h2 = ar * Hr - ai * Hi + xcr;
        Hi = ar * Hi + ai * Hr + xci; Hr = h2;
        if (FINAL) {
            xhb[m * 2048 + c] = f2b(Hr);
            xhb[m * 2048 + c + 1024] = f2b(Hi);
        } else {
            const float a2 = ar * Ar - ai * Ai; Ai = ar * Ai + ai * Ar; Ar = a2;
        }
    }
    if (!FINAL) {
        const int s = chunk * 4096 + b * 1024 + c;
        carryA[s] = make_float2(Ar, Ai);
        carryH[s] = make_float2(Hr, Hi);
    } else if (chunk == 63) {
        hlast[b * 2048 + c] = Hr;
        hlast[b * 2048 + c + 1024] = Hi;
    }
}

__global__ void scan_top(const float2* __restrict__ cA, const float2* __restrict__ cH,
                         float2* __restrict__ pH) {
    const int s = blockIdx.x * 256 + threadIdx.x;  // 4096 streams
    float pr = 0.f, pi = 0.f;
    for (int ch = 0; ch < 64; ++ch) {
        pH[ch * 4096 + s] = make_float2(pr, pi);
        float2 A = cA[ch * 4096 + s];
        float2 H = cH[ch * 4096 + s];
        float t = A.x * pr - A.y * pi + H.x;
        pi = A.x * pi + A.y * pr + H.y;
        pr = t;
    }
}

__global__ void ws_report_kernel(float* out, float code) {
    out[blockIdx.x * 256 + threadIdx.x] = code;
}

// ---------------- launch ----------------
extern "C" void kernel_launch(void* const* d_in, const int* in_sizes, int n_in,
                              void* d_out, int out_size, void* d_ws, size_t ws_size,
                              hipStream_t stream) {
    const float* x     = (const float*)d_in[0];
    const float* w_in  = (const float*)d_in[1];
    const float* b_in  = (const float*)d_in[2];
    const float* w_gx  = (const float*)d_in[3];
    const float* b_gx  = (const float*)d_in[4];
    const float* w_ga  = (const float*)d_in[5];
    const float* b_ga  = (const float*)d_in[6];
    const float* arp   = (const float*)d_in[7];
    const float* aip   = (const float*)d_in[8];
    const float* w_out = (const float*)d_in[9];
    const float* b_out = (const float*)d_in[10];
    float* out = (float*)d_out;

    // ---- workspace layout (~143 MB) ----
    char* p = (char*)d_ws;
    ushort* R0    = (ushort*)p; p += 67108864;
    ushort* xb    = R0;                          // 16384x1024 bf16 (phase A)
    ushort* gxga  = R0;                          // 16384x1024x2 bf16 interleaved (phase B)
    ushort* xhb   = (ushort*)p; p += 67108864;   // 16384x2048 bf16, then h_m in place
    ushort* w_inT = (ushort*)p; p += 4194304;
    ushort* w_outT= (ushort*)p; p += 4194304;
    ushort* WgT   = (ushort*)p; p += 1048576;
    float*  bg    = (float*)p;  p += 8192;
    float*  sp    = (float*)p;  p += 4096;
    float2* cA    = (float2*)p; p += 2097152;
    float2* cH    = (float2*)p; p += 2097152;
    float2* pH    = (float2*)p; p += 2097152;
    size_t need = (size_t)(p - (char*)d_ws);
    if (ws_size < need) {
        float code = 1000.0f + (float)(ws_size >> 20);
        ws_report_kernel<<<64, 256, 0, stream>>>(out, code);
        return;
    }

    cvt_x_kernel<<<16384, 256, 0, stream>>>((const float4*)x, (ushort4*)xb);
    transpose_cvt<<<dim3(32, 16, 1), 256, 0, stream>>>(w_in, w_inT, 1024, 2048, 1024, 0, 0);
    transpose_cvt<<<dim3(16, 32, 1), 256, 0, stream>>>(w_out, w_outT, 2048, 1024, 2048, 0, 0);
    transpose_cvt<<<dim3(2, 4, 8), 256, 0, stream>>>(w_gx, WgT, 256, 128, 256, 32768, 65536);
    transpose_cvt<<<dim3(2, 4, 8), 256, 0, stream>>>(w_ga, WgT + 32768, 256, 128, 256, 32768, 65536);
    prep_small_kernel<<<8, 256, 0, stream>>>(b_gx, b_ga, arp, bg, sp);

    // xh = x @ w_in + b_in  (bf16)   tiles 64x8 = 512 blocks, GX=8
    gemm8p<0><<<512, 512, 0, stream>>>(xb, w_inT, 16384, 2048, 1024, 1024, 1024, 3,
                                       b_in, nullptr, xhb);
    // gates = sigmoid(blockdiag(xh)) -> interleaved (gx,ga) over R0   GX=16
    gemm_bt<1><<<2048, 256, 0, stream>>>(xhb, WgT, 16384, 2048, 256, 2048, 256, 4,
                                         bg, nullptr, gxga);
    // scan
    scan_chunk<0><<<dim3(64, 4, 4), 256, 0, stream>>>((const ushort2*)gxga, xhb, sp, aip,
                                                      cA, cH, nullptr, nullptr);
    scan_top<<<16, 256, 0, stream>>>(cA, cH, pH);
    scan_chunk<1><<<dim3(64, 4, 4), 256, 0, stream>>>((const ushort2*)gxga, xhb, sp, aip,
                                                      nullptr, nullptr, pH, out + 16777216);
    // y = h_m @ w_out + b_out   tiles 64x4 = 256 blocks, GX=4 -> gxbits=2
    gemm8p<2><<<256, 512, 0, stream>>>(xhb, w_outT, 16384, 1024, 2048, 2048, 2048, 2,
                                       b_out, out, nullptr);
}